// Round 4
// baseline (66.520 us; speedup 1.0000x reference)
//
#include <hip/hip_runtime.h>

#define HH 128
#define WW 128
#define HWSZ (HH*WW)
#define NB 4
#define CIN 64
#define COUT 64
#define KK 9
#define XSTR 72   // NHWC channel stride in bf16 elements (144 B, 16B-aligned)

typedef short bf16x8 __attribute__((ext_vector_type(8)));
typedef float f32x4 __attribute__((ext_vector_type(4)));

union U4 { uint4 v; unsigned a[4]; };

__device__ __forceinline__ short f2bf(float f) {
    union { float f; unsigned u; } v; v.f = f;
    unsigned r = v.u + 0x7FFFu + ((v.u >> 16) & 1u);
    return (short)(r >> 16);
}
__device__ __forceinline__ float bflo(unsigned dw) {
    union { unsigned u; float f; } v; v.u = dw << 16; return v.f;
}
__device__ __forceinline__ float bfhi(unsigned dw) {
    union { unsigned u; float f; } v; v.u = dw & 0xFFFF0000u; return v.f;
}
__device__ __forceinline__ unsigned cvtpk(float lo, float hi) {
    unsigned r;
    asm("v_cvt_pk_bf16_f32 %0, %1, %2" : "=v"(r) : "v"(lo), "v"(hi));
    return r;
}

// ---------------- prep: NHWC-bf16 transpose (blocks 0..1023) + weight repack ----------------
// xt: [NB*HWSZ][XSTR] bf16, channels 0..63 real, 64..71 zero pad
// wd: deform B frags  [(tap*2+ks)*4+nt][64][8]
// wc: conv   B frags  [(tap*2+ks)*2+nt][64][8]
// wmf: f32 [tap][nt][64]: conv weight for input mask channel (c=64)
__global__ __launch_bounds__(256) void prep_kernel(
    const float* __restrict__ input,
    const float* __restrict__ weight,
    const float* __restrict__ offset_w,
    const float* __restrict__ mask_w,
    short* __restrict__ xt,
    short* __restrict__ wd,
    short* __restrict__ wc,
    float* __restrict__ wmf)
{
    __shared__ short lds[64 * 82];
    int bid = blockIdx.x;
    if (bid < 1024) {
        int g0 = bid * 64;
        int b  = g0 >> 14;
        int p0 = g0 & (HWSZ - 1);
        int px = threadIdx.x & 63;
        int cq = threadIdx.x >> 6;
#pragma unroll
        for (int it = 0; it < 16; ++it) {
            int c = it * 4 + cq;
            float v = input[((size_t)(b * 64 + c)) * HWSZ + p0 + px];
            lds[px * 82 + c] = f2bf(v);
        }
#pragma unroll
        for (int it = 0; it < 2; ++it) {
            int c = 64 + it * 4 + cq;
            lds[px * 82 + c] = 0;
        }
        __syncthreads();
#pragma unroll
        for (int it = 0; it < 3; ++it) {
            int idx = it * 256 + threadIdx.x;
            if (idx < 576) {
                int ppx = idx / 9, s = idx - ppx * 9;
                bf16x8 v = *(const bf16x8*)&lds[ppx * 82 + s * 8];
                *(bf16x8*)&xt[((size_t)(g0 + ppx)) * XSTR + s * 8] = v;
            }
        }
    } else {
        int idx = (bid - 1024) * 256 + threadIdx.x;   // 0..36863
        if (idx < 36864) {
            int j  = idx & 7;
            int l  = (idx >> 3) & 63;
            int nt = (idx >> 9) & 3;
            int ks = (idx >> 11) & 1;
            int tap = idx >> 12;
            int o = nt * 16 + (l & 15);
            int c = ks * 32 + ((l >> 4) & 3) * 8 + j;
            wd[idx] = f2bf(weight[(o * 64 + c) * 9 + tap]);
        }
        if (idx < 18432) {
            int j  = idx & 7;
            int l  = (idx >> 3) & 63;
            int nt = (idx >> 9) & 1;
            int ks = (idx >> 10) & 1;
            int tap = idx >> 11;
            int o = nt * 16 + (l & 15);
            int c = ks * 32 + ((l >> 4) & 3) * 8 + j;
            float v = 0.f;
            if (o < 18)      v = offset_w[(o * 65 + c) * 9 + tap];
            else if (o < 27) v = mask_w[((o - 18) * 65 + c) * 9 + tap];
            wc[idx] = f2bf(v);
        }
        if (idx < 1152) {
            int l  = idx & 63;
            int nt = (idx >> 6) & 1;
            int tap = idx >> 7;
            int o = nt * 16 + (l & 15);
            float v = 0.f;
            if (o < 18)      v = offset_w[(o * 65 + 64) * 9 + tap];
            else if (o < 27) v = mask_w[((o - 18) * 65 + 64) * 9 + tap];
            wmf[idx] = v;
        }
    }
}

// ---------------- conv (65ch in, 27ch out, 3x3, pad 1) via MFMA; K-split 8 waves ----------------
__global__ __launch_bounds__(512, 8) void conv_offset_mfma(
    const short* __restrict__ xt, const float* __restrict__ mask_in,
    const bf16x8* __restrict__ wc, const float* __restrict__ wmf,
    const float* __restrict__ offset_b, const float* __restrict__ mask_b,
    float* __restrict__ off_out, float* __restrict__ mm_out)
{
    __shared__ float redc[4][8][64];
    int wid = threadIdx.x >> 6;
    int lane = threadIdx.x & 63;
    int tile = wid & 3, half = wid >> 2;
    int r = lane & 15, lg = lane >> 4;
    int g0 = blockIdx.x * 64 + tile * 16;
    int gp = g0 + r;
    int b = gp >> 14, p = gp & (HWSZ - 1);
    int i = p >> 7, j = p & 127;
    const short* xb = xt + ((size_t)(b << 14)) * XSTR;

    f32x4 acc0 = {0,0,0,0}, acc1 = {0,0,0,0};

#pragma unroll
    for (int t = 0; t < 9; ++t) {
        int yy = i + t / 3 - 1, xx = j + t % 3 - 1;
        bool valid = ((unsigned)yy < HH) && ((unsigned)xx < WW);
        int nb = yy * WW + xx;
        const short* ap = xb + (size_t)(valid ? nb : 0) * XSTR + half * 32 + lg * 8;
        union { bf16x8 s; uint4 u; } A;
        A.u = *(const uint4*)ap;
        if (!valid) { A.u.x = 0; A.u.y = 0; A.u.z = 0; A.u.w = 0; }
        const bf16x8* wck = wc + (t * 4 + half * 2) * 64 + lane;
        bf16x8 B0 = wck[0];
        bf16x8 B1 = wck[64];
        acc0 = __builtin_amdgcn_mfma_f32_16x16x32_bf16(A.s, B0, acc0, 0, 0, 0);
        acc1 = __builtin_amdgcn_mfma_f32_16x16x32_bf16(A.s, B1, acc1, 0, 0, 0);
    }

    if (half == 1) {
        // mask-channel (c=64) contribution in f32, folded into this half's partial
#pragma unroll
        for (int t = 0; t < 9; ++t) {
            float wv0 = wmf[(t * 2 + 0) * 64 + lane];
            float wv1 = wmf[(t * 2 + 1) * 64 + lane];
#pragma unroll
            for (int rr = 0; rr < 4; ++rr) {
                int gpix = g0 + lg * 4 + rr;
                int pb = gpix >> 14, pp = gpix & (HWSZ - 1);
                int pi = pp >> 7, pj = pp & 127;
                int yy = pi + t / 3 - 1, xx = pj + t % 3 - 1;
                bool v = ((unsigned)yy < HH) && ((unsigned)xx < WW);
                float mv = v ? mask_in[(size_t)pb * HWSZ + yy * WW + xx] : 0.f;
                acc0[rr] = fmaf(mv, wv0, acc0[rr]);
                acc1[rr] = fmaf(mv, wv1, acc1[rr]);
            }
        }
        float* rp = &redc[tile][0][lane];
#pragma unroll
        for (int q = 0; q < 4; ++q) {
            rp[q * 64]       = acc0[q];
            rp[(4 + q) * 64] = acc1[q];
        }
    }
    __syncthreads();
    if (half == 0) {
        const float* rp = &redc[tile][0][lane];
#pragma unroll
        for (int q = 0; q < 4; ++q) {
            acc0[q] += rp[q * 64];
            acc1[q] += rp[(4 + q) * 64];
        }
        int oc0 = lane & 15;
        {   // nt = 0: oc = 0..15, all offsets
            float bo = offset_b[oc0];
#pragma unroll
            for (int rr = 0; rr < 4; ++rr) {
                int gpix = g0 + lg * 4 + rr;
                int pb = gpix >> 14, pp = gpix & (HWSZ - 1);
                off_out[((size_t)(pb * 18 + oc0)) * HWSZ + pp] = acc0[rr] + bo;
            }
        }
        {   // nt = 1: oc = 16..31 (16,17 offsets; 18..26 mask)
            int oc = 16 + oc0;
            if (oc < 18) {
                float bo = offset_b[oc];
#pragma unroll
                for (int rr = 0; rr < 4; ++rr) {
                    int gpix = g0 + lg * 4 + rr;
                    int pb = gpix >> 14, pp = gpix & (HWSZ - 1);
                    off_out[((size_t)(pb * 18 + oc)) * HWSZ + pp] = acc1[rr] + bo;
                }
            } else if (oc < 27) {
                float bo = mask_b[oc - 18];
#pragma unroll
                for (int rr = 0; rr < 4; ++rr) {
                    int gpix = g0 + lg * 4 + rr;
                    int pb = gpix >> 14, pp = gpix & (HWSZ - 1);
                    float z = acc1[rr] + bo;
                    mm_out[((size_t)(pb * 9 + (oc - 18))) * HWSZ + pp] =
                        1.f / (1.f + __expf(-z));
                }
            }
        }
    }
}

// ---------------- main deformable conv: MFMA, K-split 8 waves, fused update_mask ----------------
__global__ __launch_bounds__(512, 8) void deform_main_mfma(
    const short* __restrict__ xt, const float* __restrict__ off,
    const float* __restrict__ mm, const float* __restrict__ mask_in,
    const bf16x8* __restrict__ wd, const float* __restrict__ bias,
    float* __restrict__ out, float* __restrict__ upd)
{
    __shared__ float red[4][16][64];
    int wid = threadIdx.x >> 6, lane = threadIdx.x & 63;
    int tile = wid & 3, half = wid >> 2;
    int r = lane & 15, lg = lane >> 4;
    int g0 = blockIdx.x * 64 + tile * 16;
    int gp = g0 + r;
    int b = gp >> 14, p = gp & (HWSZ - 1);
    int i = p >> 7, j = p & 127;
    const short* xb = xt + ((size_t)(b << 14)) * XSTR;
    const float* mb = mask_in + (size_t)b * HWSZ;

    f32x4 acc0 = {0,0,0,0}, acc1 = {0,0,0,0}, acc2 = {0,0,0,0}, acc3 = {0,0,0,0};
    float um = 0.f;

#pragma unroll 1
    for (int k = 0; k < KK; ++k) {
        float dy = off[(b * 18 + 2 * k) * HWSZ + p];
        float dx = off[(b * 18 + 2 * k + 1) * HWSZ + p];
        float m  = mm[(b * 9 + k) * HWSZ + p];
        float py = dy + (float)(k / 3 + i - 1);
        float px = dx + (float)(k % 3 + j - 1);
        float fy = floorf(py), fx = floorf(px);
        float wy = py - fy, wx = px - fx;
        int y0 = (int)fy, x0 = (int)fx;
        int y1 = y0 + 1, x1 = x0 + 1;
        bool vy0 = (unsigned)y0 < HH, vy1 = (unsigned)y1 < HH;
        bool vx0 = (unsigned)x0 < WW, vx1 = (unsigned)x1 < WW;
        int yc0 = min(max(y0, 0), HH - 1), yc1 = min(max(y1, 0), HH - 1);
        int xc0 = min(max(x0, 0), WW - 1), xc1 = min(max(x1, 0), WW - 1);
        float r00 = (vy0 && vx0) ? (1 - wy) * (1 - wx) : 0.f;
        float r01 = (vy0 && vx1) ? (1 - wy) * wx : 0.f;
        float r10 = (vy1 && vx0) ? wy * (1 - wx) : 0.f;
        float r11 = (vy1 && vx1) ? wy * wx : 0.f;
        int i00 = yc0 * WW + xc0, i01 = yc0 * WW + xc1;
        int i10 = yc1 * WW + xc0, i11 = yc1 * WW + xc1;

        if (half == 0)
            um += r00 * mb[i00] + r01 * mb[i01] + r10 * mb[i10] + r11 * mb[i11];

        float w00 = r00 * m, w01 = r01 * m, w10 = r10 * m, w11 = r11 * m;

        int co = half * 32 + lg * 8;
        U4 c00, c01, c10, c11;
        c00.v = *(const uint4*)(xb + (size_t)i00 * XSTR + co);
        c01.v = *(const uint4*)(xb + (size_t)i01 * XSTR + co);
        c10.v = *(const uint4*)(xb + (size_t)i10 * XSTR + co);
        c11.v = *(const uint4*)(xb + (size_t)i11 * XSTR + co);
        union { bf16x8 s; unsigned u[4]; } A;
#pragma unroll
        for (int q = 0; q < 4; ++q) {
            unsigned d00 = c00.a[q], d01 = c01.a[q], d10 = c10.a[q], d11 = c11.a[q];
            float vlo = fmaf(w00, bflo(d00), fmaf(w01, bflo(d01),
                        fmaf(w10, bflo(d10), w11 * bflo(d11))));
            float vhi = fmaf(w00, bfhi(d00), fmaf(w01, bfhi(d01),
                        fmaf(w10, bfhi(d10), w11 * bfhi(d11))));
            A.u[q] = cvtpk(vlo, vhi);
        }
        const bf16x8* wbk = wd + (k * 8 + half * 4) * 64 + lane;
        bf16x8 B0 = wbk[0];
        bf16x8 B1 = wbk[64];
        bf16x8 B2 = wbk[128];
        bf16x8 B3 = wbk[192];
        acc0 = __builtin_amdgcn_mfma_f32_16x16x32_bf16(A.s, B0, acc0, 0, 0, 0);
        acc1 = __builtin_amdgcn_mfma_f32_16x16x32_bf16(A.s, B1, acc1, 0, 0, 0);
        acc2 = __builtin_amdgcn_mfma_f32_16x16x32_bf16(A.s, B2, acc2, 0, 0, 0);
        acc3 = __builtin_amdgcn_mfma_f32_16x16x32_bf16(A.s, B3, acc3, 0, 0, 0);
    }

    if (half == 1) {
        float* rp = &red[tile][0][lane];
#pragma unroll
        for (int q = 0; q < 4; ++q) {
            rp[q * 64]        = acc0[q];
            rp[(4 + q) * 64]  = acc1[q];
            rp[(8 + q) * 64]  = acc2[q];
            rp[(12 + q) * 64] = acc3[q];
        }
    }
    __syncthreads();
    if (half == 0) {
        const float* rp = &red[tile][0][lane];
#pragma unroll
        for (int q = 0; q < 4; ++q) {
            acc0[q] += rp[q * 64];
            acc1[q] += rp[(4 + q) * 64];
            acc2[q] += rp[(8 + q) * 64];
            acc3[q] += rp[(12 + q) * 64];
        }

        um = fminf(fmaxf(64.f * um, 0.f), 1.f);
        if (lane < 16) upd[g0 + lane] = um;

        int oc = lane & 15;
        int pr0 = lg * 4;
        float u[4];
#pragma unroll
        for (int rr = 0; rr < 4; ++rr) u[rr] = __shfl(um, pr0 + rr, 64);

#define STORE_NT(ACC, NT)                                                     \
        {                                                                     \
            float bo = bias[(NT) * 16 + oc];                                  \
            _Pragma("unroll")                                                 \
            for (int rr = 0; rr < 4; ++rr) {                                  \
                int gg = g0 + pr0 + rr;                                       \
                int bb = gg >> 14;                                            \
                int pp = gg & (HWSZ - 1);                                     \
                out[((size_t)(bb * 64 + (NT) * 16 + oc)) * HWSZ + pp] =       \
                    (ACC[rr] + bo) * u[rr];                                   \
            }                                                                 \
        }
        STORE_NT(acc0, 0)
        STORE_NT(acc1, 1)
        STORE_NT(acc2, 2)
        STORE_NT(acc3, 3)
#undef STORE_NT
    }
}

extern "C" void kernel_launch(void* const* d_in, const int* in_sizes, int n_in,
                              void* d_out, int out_size, void* d_ws, size_t ws_size,
                              hipStream_t stream) {
    const float* input    = (const float*)d_in[0];
    const float* mask_in  = (const float*)d_in[1];
    const float* weight   = (const float*)d_in[2];
    const float* bias     = (const float*)d_in[3];
    const float* offset_w = (const float*)d_in[4];
    const float* offset_b = (const float*)d_in[5];
    const float* mask_w   = (const float*)d_in[6];
    const float* mask_b   = (const float*)d_in[7];

    float* out = (float*)d_out;
    float* upd = out + (size_t)NB * COUT * HWSZ;

    float* ws = (float*)d_ws;
    float* off_ws = ws;                                       // 1,179,648 f
    float* mm_ws  = off_ws + (size_t)NB * 18 * HWSZ;          //   589,824 f
    float* wmf    = mm_ws + (size_t)NB * 9 * HWSZ;            //     1,152 f
    short* wd     = (short*)(wmf + 1152);                     //    36,864 bf16
    short* wc     = wd + 36864;                               //    18,432 bf16
    short* xt     = wc + 18432;                               // 4,718,592 bf16

    hipLaunchKernelGGL(prep_kernel, dim3(1168), dim3(256), 0, stream,
                       input, weight, offset_w, mask_w, xt, wd, wc, wmf);
    hipLaunchKernelGGL(conv_offset_mfma, dim3(1024), dim3(512), 0, stream,
                       xt, mask_in, (const bf16x8*)wc, wmf, offset_b, mask_b,
                       off_ws, mm_ws);
    hipLaunchKernelGGL(deform_main_mfma, dim3(1024), dim3(512), 0, stream,
                       xt, off_ws, mm_ws, mask_in, (const bf16x8*)wd, bias,
                       out, upd);
}